// Round 1
// baseline (2051.279 us; speedup 1.0000x reference)
//
#include <hip/hip_runtime.h>
#include <hip/hip_bf16.h>

typedef __attribute__((ext_vector_type(4))) float f32x4;
typedef __attribute__((ext_vector_type(8))) short short8;

__device__ __forceinline__ short f2bf(float f) {
    union { __hip_bfloat16 h; short s; } u;
    u.h = __float2bfloat16(f);
    return u.s;
}

// Stage 1: x = features @ W, stored transposed bf16: xT[f][k] = x[k][f]
// grid: (n/256, 32), block 256. f = blockIdx.y (wave-uniform -> W loads are scalar).
__global__ void stage1_xw(const float* __restrict__ features,
                          const float* __restrict__ Wm,
                          __hip_bfloat16* __restrict__ xT, int n) {
    int k = blockIdx.x * blockDim.x + threadIdx.x;
    int f = blockIdx.y;
    const float* frow = features + (size_t)k * 32;
    float acc = 0.f;
#pragma unroll
    for (int c = 0; c < 32; ++c) acc += frow[c] * Wm[c * 32 + f];
    xT[(size_t)f * n + k] = __float2bfloat16(acc);
}

// Big skinny GEMM: out = A[n][n] @ BT^T  (BT is [32][n] bf16, pre-transposed).
// STAGE2: out = yT bf16 [32][n], scaled by diag.  else: out = fp32 [n][32] (d_out).
// Block: 256 thr = 4 waves. Each block owns 16 output rows; waves split K 4-ways.
template <bool STAGE2>
__global__ __launch_bounds__(256, 4)
void hwnn_gemm(const float* __restrict__ A,
               const __hip_bfloat16* __restrict__ BT,
               const float* __restrict__ diag,
               void* __restrict__ outp, int n) {
    const int tid  = threadIdx.x;
    const int lane = tid & 63;
    const int w    = tid >> 6;     // wave id 0..3 (K-split)
    const int m    = lane & 15;    // A row / B col within tile
    const int q    = lane >> 4;    // k-chunk selector
    const int i0   = blockIdx.x * 16;

    const int kspan = n >> 2;        // 4096
    const int kbase = w * kspan;

    // A fragment: lane needs A[i0+m][k0 + q*8 .. +7]  (8 consecutive fp32 = 2 float4)
    const f32x4* ap = (const f32x4*)(A + (size_t)(i0 + m) * n + kbase + q * 8);
    // B fragments: lane needs BT[n_col][k0 + q*8 .. +7] (8 consecutive bf16 = 16B)
    const short* bbase = (const short*)BT;
    const short8* b0p = (const short8*)(bbase + (size_t)m * n + kbase + q * 8);
    const short8* b1p = (const short8*)(bbase + (size_t)(16 + m) * n + kbase + q * 8);

    f32x4 acc0 = {0.f, 0.f, 0.f, 0.f};
    f32x4 acc1 = {0.f, 0.f, 0.f, 0.f};

    const int steps = kspan >> 5;   // 128 k-steps of 32
#pragma unroll 4
    for (int s = 0; s < steps; ++s) {
        f32x4 alo = ap[0];
        f32x4 ahi = ap[1];
        short8 b0 = b0p[0];
        short8 b1 = b1p[0];
        short8 af;
        af[0] = f2bf(alo[0]); af[1] = f2bf(alo[1]);
        af[2] = f2bf(alo[2]); af[3] = f2bf(alo[3]);
        af[4] = f2bf(ahi[0]); af[5] = f2bf(ahi[1]);
        af[6] = f2bf(ahi[2]); af[7] = f2bf(ahi[3]);
        acc0 = __builtin_amdgcn_mfma_f32_16x16x32_bf16(af, b0, acc0, 0, 0, 0);
        acc1 = __builtin_amdgcn_mfma_f32_16x16x32_bf16(af, b1, acc1, 0, 0, 0);
        ap  += 8;   // 32 floats
        b0p += 4;   // 32 bf16
        b1p += 4;
    }

    // Reduce the 4 K-partials via LDS. C/D layout: col = lane&15, row = q*4 + reg.
    __shared__ float part[4][16][33];
#pragma unroll
    for (int r = 0; r < 4; ++r) {
        part[w][q * 4 + r][m]      = acc0[r];
        part[w][q * 4 + r][16 + m] = acc1[r];
    }
    __syncthreads();

    if constexpr (STAGE2) {
        __hip_bfloat16* yT = (__hip_bfloat16*)outp;
#pragma unroll
        for (int e = tid; e < 512; e += 256) {
            int row = e & 15, col = e >> 4;   // consecutive tid -> consecutive rows (coalesced-ish)
            float s = part[0][row][col] + part[1][row][col] +
                      part[2][row][col] + part[3][row][col];
            s *= diag[i0 + row];
            yT[(size_t)col * n + (i0 + row)] = __float2bfloat16(s);
        }
    } else {
        float* out = (float*)outp;
#pragma unroll
        for (int e = tid; e < 512; e += 256) {
            int row = e >> 5, col = e & 31;   // consecutive tid -> consecutive addr (coalesced)
            float s = part[0][row][col] + part[1][row][col] +
                      part[2][row][col] + part[3][row][col];
            out[(size_t)(i0 + row) * 32 + col] = s;
        }
    }
}

extern "C" void kernel_launch(void* const* d_in, const int* in_sizes, int n_in,
                              void* d_out, int out_size, void* d_ws, size_t ws_size,
                              hipStream_t stream) {
    const float* features     = (const float*)d_in[0];
    const float* wavelets     = (const float*)d_in[1];
    const float* wavelets_inv = (const float*)d_in[2];
    const float* diag         = (const float*)d_in[3];
    const float* Wm           = (const float*)d_in[4];
    const int n = in_sizes[3];    // diag_filter has N elements

    __hip_bfloat16* xT = (__hip_bfloat16*)d_ws;                // [32][n] bf16, 1 MB
    __hip_bfloat16* yT = xT + (size_t)32 * n;                  // [32][n] bf16, 1 MB

    // Stage 1: x = features @ W  (transposed bf16 out)
    stage1_xw<<<dim3(n / 256, 32), 256, 0, stream>>>(features, Wm, xT, n);
    // Stage 2: yT = diag * (wavelets_inv @ x)
    hwnn_gemm<true><<<n / 16, 256, 0, stream>>>(wavelets_inv, xT, diag, (void*)yT, n);
    // Stage 3: out = wavelets @ y
    hwnn_gemm<false><<<n / 16, 256, 0, stream>>>(wavelets, yT, nullptr, d_out, n);
}